// Round 14
// baseline (157.911 us; speedup 1.0000x reference)
//
#include <hip/hip_runtime.h>

#define NUM_NODES 100000
#define NUM_EDGES 400000
#define F_IN 16
#define F_EDGE 8
#define EMB 16
#define NUM_GRAPHS 256

#define EDGE_TILES 10                                  // 32-edge tiles per block
#define EDGE_BLOCKS (NUM_EDGES / (32 * EDGE_TILES))    // 1250

// ---------------------------------------------------------------------------
// Workspace (zeroed each launch): sums : NUM_NODES*EMB f32, cnt : NUM_NODES f32
// ---------------------------------------------------------------------------

// v13 edge kernel = the v8 champion (50.3 us, VGPR 80, zero spill) with ONE
// change: EDGE_TILES 5 -> 10 (2500 -> 1250 blocks). Rationale: the kernel is
// latency-bound (VALU 52%, HBM 15%) and each block pays a ~1-2 us serial
// startup (weight load -> LDS -> barrier -> bias read); at ~2 resident
// blocks/CU each CU runs ~10 blocks sequentially, so ~5-10 us of the 51 us
// is repeated startup. Halving block count halves that, touching nothing
// else. srcT grows +10 regs (~90 live; v1 ran clean at 108, below spill
// territory). 1250 blocks = 4.9/CU, still ample TLP.
//
// Everything else is the locked champion config (full matrix in R12 notes):
//  - 2-edge fenced dbuf pipeline: the only pipeline shape the default
//    allocator HOLDS (fenced live set < ~60 regs); bigger sets spill
//    (84-VGPR anchor) and waves_per_eu pins cost the occupancy that
//    latency-hiding needs.
//  - o = tid&15: 16 contiguous lanes per 64B sums-row atomic (v4 violated
//    it: WRITE doubled).
//  - per-(edge,o) FMA order bit-exact since v1 (absmax 0.0 all rounds).
__global__ __launch_bounds__(256, 3) void edge_kernel(
    const float* __restrict__ x, const int* __restrict__ ei,
    const float* __restrict__ ea, const float* __restrict__ nn1_w,
    const float* __restrict__ nn1_b, float* __restrict__ sums,
    float* __restrict__ cnt)
{
    __shared__ float wtp[256 * 12];   // row r=(i*16+o): 8 weights + 4 pad
    __shared__ float btp[16 * 20];    // btp[o*20+i]

    const int tid = threadIdx.x;
    const int eL  = tid >> 4;
    const int o   = tid & 15;         // LOW bits: atomic-coalescing invariant
    const int eb0 = blockIdx.x * EDGE_TILES * 32;

    // ---- issue all src-index loads immediately (latency hides under staging)
    int srcA[EDGE_TILES], srcB[EDGE_TILES];
    #pragma unroll
    for (int t = 0; t < EDGE_TILES; t++) {
        srcA[t] = ei[eb0 + t * 32 + eL];
        srcB[t] = ei[eb0 + t * 32 + 16 + eL];
    }
    __builtin_amdgcn_sched_barrier(0);   // pin: src loads issue FIRST

    // ---- stage weights, vectorized (row stride 12 floats: 2-way bank = free)
    {
        const float4 w0 = *(const float4*)&nn1_w[tid * 8];
        const float4 w1 = *(const float4*)&nn1_w[tid * 8 + 4];
        *(float4*)&wtp[tid * 12]     = w0;
        *(float4*)&wtp[tid * 12 + 4] = w1;
    }
    btp[(tid & 15) * 20 + (tid >> 4)] = nn1_b[tid];   // tid = i*16+o
    __syncthreads();                                   // the ONLY barrier

    float br[F_IN];
    #pragma unroll
    for (int r = 0; r < 4; r++) {
        const float4 b4 = *(const float4*)&btp[o * 20 + 4 * r];
        br[4 * r + 0] = b4.x; br[4 * r + 1] = b4.y;
        br[4 * r + 2] = b4.z; br[4 * r + 3] = b4.w;
    }

    // ---- double-buffered tile state (p = even tiles, q = odd tiles)
    float4 pA00, pA01, pA10, pA11; float pX0[16], pX1[16]; int pDA, pDB;
    float4 qA00, qA01, qA10, qA11; float qX0[16], qX1[16]; int qDA, qDB;

#define LOAD_TILE(T, A00, A01, A10, A11, X0, X1, DA, DB) do {               \
        const int eA_ = eb0 + (T) * 32 + eL;                                \
        const int eB_ = eA_ + 16;                                           \
        DA = ei[NUM_EDGES + eA_];                                           \
        DB = ei[NUM_EDGES + eB_];                                           \
        A00 = *(const float4*)&ea[eA_ * 8];                                 \
        A01 = *(const float4*)&ea[eA_ * 8 + 4];                             \
        A10 = *(const float4*)&ea[eB_ * 8];                                 \
        A11 = *(const float4*)&ea[eB_ * 8 + 4];                             \
        _Pragma("unroll")                                                   \
        for (int r = 0; r < 4; r++) {                                       \
            const float4 v0 = *(const float4*)&x[srcA[T] * 16 + 4 * r];     \
            const float4 v1 = *(const float4*)&x[srcB[T] * 16 + 4 * r];     \
            X0[4*r+0] = v0.x; X0[4*r+1] = v0.y;                             \
            X0[4*r+2] = v0.z; X0[4*r+3] = v0.w;                             \
            X1[4*r+0] = v1.x; X1[4*r+1] = v1.y;                             \
            X1[4*r+2] = v1.z; X1[4*r+3] = v1.w;                             \
        }                                                                   \
    } while (0)

#define COMPUTE_TILE(A00, A01, A10, A11, X0, X1, DA, DB) do {               \
        float acc0 = 0.f, acc1 = 0.f;                                       \
        _Pragma("unroll")                                                   \
        for (int i = 0; i < F_IN; i++) {                                    \
            const float* wr = &wtp[(i * 16 + o) * 12];                      \
            const float4 w0 = *(const float4*)wr;                           \
            const float4 w1 = *(const float4*)(wr + 4);                     \
            float u = br[i];                                                \
            u = fmaf(A00.x, w0.x, u); u = fmaf(A00.y, w0.y, u);             \
            u = fmaf(A00.z, w0.z, u); u = fmaf(A00.w, w0.w, u);             \
            u = fmaf(A01.x, w1.x, u); u = fmaf(A01.y, w1.y, u);             \
            u = fmaf(A01.z, w1.z, u); u = fmaf(A01.w, w1.w, u);             \
            acc0 = fmaf(X0[i], fmaxf(u, 0.f), acc0);                        \
            float v = br[i];                                                \
            v = fmaf(A10.x, w0.x, v); v = fmaf(A10.y, w0.y, v);             \
            v = fmaf(A10.z, w0.z, v); v = fmaf(A10.w, w0.w, v);             \
            v = fmaf(A11.x, w1.x, v); v = fmaf(A11.y, w1.y, v);             \
            v = fmaf(A11.w, w1.w, v); v = fmaf(A11.z, w1.z, v);             \
            acc1 = fmaf(X1[i], fmaxf(v, 0.f), acc1);                        \
        }                                                                   \
        atomicAdd(&sums[DA * 16 + o], acc0);                                \
        atomicAdd(&sums[DB * 16 + o], acc1);                                \
        if (o == 0) {                                                       \
            atomicAdd(&cnt[DA], 1.f);                                       \
            atomicAdd(&cnt[DB], 1.f);                                       \
        }                                                                   \
    } while (0)

    LOAD_TILE(0, pA00, pA01, pA10, pA11, pX0, pX1, pDA, pDB);
    #pragma unroll
    for (int t = 0; t < EDGE_TILES; t++) {
        if ((t & 1) == 0) {
            if (t + 1 < EDGE_TILES)
                LOAD_TILE(t + 1, qA00, qA01, qA10, qA11, qX0, qX1, qDA, qDB);
            __builtin_amdgcn_sched_barrier(0);   // loads(t+1) stay above compute(t)
            COMPUTE_TILE(pA00, pA01, pA10, pA11, pX0, pX1, pDA, pDB);
        } else {
            if (t + 1 < EDGE_TILES)
                LOAD_TILE(t + 1, pA00, pA01, pA10, pA11, pX0, pX1, pDA, pDB);
            __builtin_amdgcn_sched_barrier(0);
            COMPUTE_TILE(qA00, qA01, qA10, qA11, qX0, qX1, qDA, qDB);
        }
    }
#undef LOAD_TILE
#undef COMPUTE_TILE
}

// One block per GRAPH (batch is sorted). Replaces node_kernel + head_kernel.
// Binary-search the node range [start,end); stream nodes in 16-node tiles:
// thread (j = tid>>4, o = tid&15) computes h[base+j][o]; the x row is
// accessed via intra-wave shuffle (wave = 4 j-values x 16 o-values, so
// x[n][i] lives in lane ((j&3)<<4)|i ) -- no LDS staging, no barriers, no
// serial flusher, and NO pooling atomics: per-thread register accumulators
// -> wave tree-reduce -> cross-wave LDS reduce -> fused head MLP -> out[g].
// (Passed R3-R13 with absmax 0.0; ~8 us by arithmetic.)
__global__ __launch_bounds__(256) void graph_kernel(
    const float* __restrict__ x, const int* __restrict__ batch,
    const float* __restrict__ root_w, const float* __restrict__ conv_b,
    const float* __restrict__ sums, const float* __restrict__ cnt,
    const float* __restrict__ lin1_w, const float* __restrict__ lin1_b,
    const float* __restrict__ lin2_w, const float* __restrict__ lin2_b,
    float* __restrict__ out)
{
    __shared__ float redM[4][16];
    __shared__ float redS[4][16];

    const int g   = blockIdx.x;
    const int tid = threadIdx.x;
    const int j   = tid >> 4;
    const int o   = tid & 15;
    const int jw  = j & 3;             // j within the 64-lane wave

    // root_w row o into registers: rwr[i] = root_w[o*16+i]
    float rwr[F_IN];
    #pragma unroll
    for (int r = 0; r < 4; r++) {
        const float4 v = *(const float4*)&root_w[o * 16 + 4 * r];
        rwr[4*r+0] = v.x; rwr[4*r+1] = v.y; rwr[4*r+2] = v.z; rwr[4*r+3] = v.w;
    }
    const float cb = conv_b[o];

    // Interleaved binary searches (batch sorted, block-uniform -> no
    // divergence; the two dependent-load chains overlap each other):
    //   start = lower_bound(batch, g), end = lower_bound(batch, g+1)
    int lo0 = 0, hi0 = NUM_NODES, lo1 = 0, hi1 = NUM_NODES;
    while (lo0 < hi0 || lo1 < hi1) {
        const int m0 = (lo0 + hi0) >> 1;
        const int m1 = (lo1 + hi1) >> 1;
        int b0 = 0, b1 = 0;
        if (lo0 < hi0) b0 = batch[m0];
        if (lo1 < hi1) b1 = batch[m1];
        if (lo0 < hi0) { if (b0 < g)     lo0 = m0 + 1; else hi0 = m0; }
        if (lo1 < hi1) { if (b1 < g + 1) lo1 = m1 + 1; else hi1 = m1; }
    }
    const int start = lo0, end = lo1;

    float am = 0.f, asum = 0.f;        // h >= 0, so 0 is a valid max identity

    // software-pipelined main loop (prefetch next tile's 3 loads)
    int base = start;
    float xv = 0.f, sv = 0.f, cv = 1.f;
    if (base < end) {
        const int n = base + j;
        const bool v = n < end;
        xv = v ? x[n * 16 + o]    : 0.f;
        sv = v ? sums[n * 16 + o] : 0.f;
        cv = v ? cnt[n]           : 1.f;
    }
    while (base < end) {
        const int nbase = base + 16;
        float xv1 = 0.f, sv1 = 0.f, cv1 = 1.f;
        if (nbase < end) {
            const int n1 = nbase + j;
            const bool v1 = n1 < end;
            xv1 = v1 ? x[n1 * 16 + o]    : 0.f;
            sv1 = v1 ? sums[n1 * 16 + o] : 0.f;
            cv1 = v1 ? cnt[n1]           : 1.f;
        }
        __builtin_amdgcn_sched_barrier(0);   // prefetch issues before compute

        // h-FMA order identical to old node_kernel (bit-exact per element)
        float a = cb + sv / fmaxf(cv, 1.f);
        #pragma unroll
        for (int i = 0; i < F_IN; i++)
            a = fmaf(__shfl(xv, (jw << 4) | i, 64), rwr[i], a);
        const bool v = (base + j) < end;
        const float h = v ? fmaxf(a, 0.f) : 0.f;
        am = fmaxf(am, h);
        asum += h;

        xv = xv1; sv = sv1; cv = cv1;
        base = nbase;
    }

    // reduce over j: butterfly within wave (j&3), then across 4 waves via LDS
    am   = fmaxf(am, __shfl_xor(am, 16, 64));
    am   = fmaxf(am, __shfl_xor(am, 32, 64));
    asum = asum + __shfl_xor(asum, 16, 64);
    asum = asum + __shfl_xor(asum, 32, 64);
    const int w = tid >> 6;
    if ((tid & 63) < 16) { redM[w][o] = am; redS[w][o] = asum; }
    __syncthreads();

    if (tid < 64) {                     // wave 0: final reduce + head MLP
        const int k = tid & 15;
        const float amF = fmaxf(fmaxf(redM[0][k], redM[1][k]),
                                fmaxf(redM[2][k], redM[3][k]));
        const float asF = (redS[0][k] + redS[1][k]) + (redS[2][k] + redS[3][k]);
        const float c   = fmaxf((float)(end - start), 1.f);
        const float mnF = asF / c;

        // lane k computes a_k; inner cc order matches old head_kernel
        float a = lin1_b[k];
        #pragma unroll
        for (int cc = 0; cc < 16; cc++)
            a = fmaf(__shfl(amF, cc, 64), lin1_w[k * 32 + cc], a);
        #pragma unroll
        for (int cc = 0; cc < 16; cc++)
            a = fmaf(__shfl(mnF, cc, 64), lin1_w[k * 32 + 16 + cc], a);
        const float ra = fmaxf(a, 0.f);

        // serial k-accumulation (same order as old head_kernel)
        float acc = lin2_b[0];
        #pragma unroll
        for (int k2 = 0; k2 < 16; k2++)
            acc = fmaf(__shfl(ra, k2, 64), lin2_w[k2], acc);
        if (tid == 0) out[g] = acc;
    }
}

extern "C" void kernel_launch(void* const* d_in, const int* in_sizes, int n_in,
                              void* d_out, int out_size, void* d_ws, size_t ws_size,
                              hipStream_t stream) {
    const float* x      = (const float*)d_in[0];
    const int*   ei     = (const int*)d_in[1];
    const float* ea     = (const float*)d_in[2];
    const int*   batch  = (const int*)d_in[3];
    const float* nn1_w  = (const float*)d_in[4];
    const float* nn1_b  = (const float*)d_in[5];
    const float* root_w = (const float*)d_in[6];
    const float* conv_b = (const float*)d_in[7];
    const float* lin1_w = (const float*)d_in[8];
    const float* lin1_b = (const float*)d_in[9];
    const float* lin2_w = (const float*)d_in[10];
    const float* lin2_b = (const float*)d_in[11];
    float* out = (float*)d_out;

    float* sums = (float*)d_ws;
    float* cnt  = sums + (size_t)NUM_NODES * EMB;

    const size_t zero_bytes = sizeof(float) * ((size_t)NUM_NODES * EMB + NUM_NODES);
    hipMemsetAsync(d_ws, 0, zero_bytes, stream);

    edge_kernel<<<EDGE_BLOCKS, 256, 0, stream>>>(x, ei, ea, nn1_w, nn1_b, sums, cnt);
    graph_kernel<<<NUM_GRAPHS, 256, 0, stream>>>(
        x, batch, root_w, conv_b, sums, cnt,
        lin1_w, lin1_b, lin2_w, lin2_b, out);
}

// Round 15
// 157.174 us; speedup vs baseline: 1.0047x; 1.0047x over previous
//
#include <hip/hip_runtime.h>

#define NUM_NODES 100000
#define NUM_EDGES 400000
#define F_IN 16
#define F_EDGE 8
#define EMB 16
#define NUM_GRAPHS 256

#define EDGE_TILES 5                                   // 32-edge tiles per block
#define EDGE_BLOCKS (NUM_EDGES / (32 * EDGE_TILES))    // 2500

// ---------------------------------------------------------------------------
// Workspace (zeroed each launch): sums : NUM_NODES*EMB f32, cnt : NUM_NODES f32
// ---------------------------------------------------------------------------

// FINAL edge kernel = v8 champion (50-53 us edge, VGPR 80, zero spill,
// WRITE 37.5 MB; total 157.4/157.5 us in R7/R13 — session best, 3rd deploy).
//
// Completed 14-round experiment matrix — every structural enlargement fails
// on the same two-sided compiler constraint:
//   2-edge+fence+default = 50 (THIS)   | 2-edge nofence        = 60
//   2-edge+wsplit+pin22  = 56          | 2-edge+wsplit+default = 147 (spill)
//   4-edge nofence+pin22 = 56          | 4-edge+fence+pin22    = 57
//   4-edge nofence+deflt = 87          | 4-edge+fence+default  = 74-80 (spill)
//   10-tile (srcT=20)    = 56 (spill: VGPR 84, WRITE +7.5MB — R14)
// Proven mechanisms bounding this space:
//  1. Default allocator anchors at 84 VGPR (512/6-waves heuristic) and
//     SPILLS any larger live set (v9's launder test: 64 asm-pinned values
//     spilled, 281MB WRITE). __launch_bounds__ cannot lift this.
//  2. amdgpu_waves_per_eu(2,2) lifts the budget (VGPR 100-104, spill-free)
//     but caps occupancy 25->16-18%, and the kernel is LATENCY-bound: the
//     lost TLP costs more than the registers gain. (LDS-bound theory
//     refuted by v12: halving ds_read changed nothing.)
//  3. IR-level load sinking defeats sched_barrier prefetch for any fenced
//     live set > ~60 regs (v11/v12: VGPR ~104 vs ~190 for a held pipeline).
// v8 is the saddle point: the largest fenced 2-deep pipeline the default
// allocator holds spill-free (live set ~60 regs) at 25% occupancy.
// Invariants: o = tid&15 (16 contiguous lanes per 64B sums-row atomic;
// v4 violated it -> WRITE doubled); FMA order bit-exact since v1.
__global__ __launch_bounds__(256, 3) void edge_kernel(
    const float* __restrict__ x, const int* __restrict__ ei,
    const float* __restrict__ ea, const float* __restrict__ nn1_w,
    const float* __restrict__ nn1_b, float* __restrict__ sums,
    float* __restrict__ cnt)
{
    __shared__ float wtp[256 * 12];   // row r=(i*16+o): 8 weights + 4 pad
    __shared__ float btp[16 * 20];    // btp[o*20+i]

    const int tid = threadIdx.x;
    const int eL  = tid >> 4;
    const int o   = tid & 15;         // LOW bits: atomic-coalescing invariant
    const int eb0 = blockIdx.x * EDGE_TILES * 32;

    // ---- issue all src-index loads immediately (latency hides under staging)
    int srcA[EDGE_TILES], srcB[EDGE_TILES];
    #pragma unroll
    for (int t = 0; t < EDGE_TILES; t++) {
        srcA[t] = ei[eb0 + t * 32 + eL];
        srcB[t] = ei[eb0 + t * 32 + 16 + eL];
    }
    __builtin_amdgcn_sched_barrier(0);   // pin: src loads issue FIRST

    // ---- stage weights, vectorized (row stride 12 floats: 2-way bank = free)
    {
        const float4 w0 = *(const float4*)&nn1_w[tid * 8];
        const float4 w1 = *(const float4*)&nn1_w[tid * 8 + 4];
        *(float4*)&wtp[tid * 12]     = w0;
        *(float4*)&wtp[tid * 12 + 4] = w1;
    }
    btp[(tid & 15) * 20 + (tid >> 4)] = nn1_b[tid];   // tid = i*16+o
    __syncthreads();                                   // the ONLY barrier

    float br[F_IN];
    #pragma unroll
    for (int r = 0; r < 4; r++) {
        const float4 b4 = *(const float4*)&btp[o * 20 + 4 * r];
        br[4 * r + 0] = b4.x; br[4 * r + 1] = b4.y;
        br[4 * r + 2] = b4.z; br[4 * r + 3] = b4.w;
    }

    // ---- double-buffered tile state (p = even tiles, q = odd tiles)
    float4 pA00, pA01, pA10, pA11; float pX0[16], pX1[16]; int pDA, pDB;
    float4 qA00, qA01, qA10, qA11; float qX0[16], qX1[16]; int qDA, qDB;

#define LOAD_TILE(T, A00, A01, A10, A11, X0, X1, DA, DB) do {               \
        const int eA_ = eb0 + (T) * 32 + eL;                                \
        const int eB_ = eA_ + 16;                                           \
        DA = ei[NUM_EDGES + eA_];                                           \
        DB = ei[NUM_EDGES + eB_];                                           \
        A00 = *(const float4*)&ea[eA_ * 8];                                 \
        A01 = *(const float4*)&ea[eA_ * 8 + 4];                             \
        A10 = *(const float4*)&ea[eB_ * 8];                                 \
        A11 = *(const float4*)&ea[eB_ * 8 + 4];                             \
        _Pragma("unroll")                                                   \
        for (int r = 0; r < 4; r++) {                                       \
            const float4 v0 = *(const float4*)&x[srcA[T] * 16 + 4 * r];     \
            const float4 v1 = *(const float4*)&x[srcB[T] * 16 + 4 * r];     \
            X0[4*r+0] = v0.x; X0[4*r+1] = v0.y;                             \
            X0[4*r+2] = v0.z; X0[4*r+3] = v0.w;                             \
            X1[4*r+0] = v1.x; X1[4*r+1] = v1.y;                             \
            X1[4*r+2] = v1.z; X1[4*r+3] = v1.w;                             \
        }                                                                   \
    } while (0)

#define COMPUTE_TILE(A00, A01, A10, A11, X0, X1, DA, DB) do {               \
        float acc0 = 0.f, acc1 = 0.f;                                       \
        _Pragma("unroll")                                                   \
        for (int i = 0; i < F_IN; i++) {                                    \
            const float* wr = &wtp[(i * 16 + o) * 12];                      \
            const float4 w0 = *(const float4*)wr;                           \
            const float4 w1 = *(const float4*)(wr + 4);                     \
            float u = br[i];                                                \
            u = fmaf(A00.x, w0.x, u); u = fmaf(A00.y, w0.y, u);             \
            u = fmaf(A00.z, w0.z, u); u = fmaf(A00.w, w0.w, u);             \
            u = fmaf(A01.x, w1.x, u); u = fmaf(A01.y, w1.y, u);             \
            u = fmaf(A01.z, w1.z, u); u = fmaf(A01.w, w1.w, u);             \
            acc0 = fmaf(X0[i], fmaxf(u, 0.f), acc0);                        \
            float v = br[i];                                                \
            v = fmaf(A10.x, w0.x, v); v = fmaf(A10.y, w0.y, v);             \
            v = fmaf(A10.z, w0.z, v); v = fmaf(A10.w, w0.w, v);             \
            v = fmaf(A11.x, w1.x, v); v = fmaf(A11.y, w1.y, v);             \
            v = fmaf(A11.w, w1.w, v); v = fmaf(A11.z, w1.z, v);             \
            acc1 = fmaf(X1[i], fmaxf(v, 0.f), acc1);                        \
        }                                                                   \
        atomicAdd(&sums[DA * 16 + o], acc0);                                \
        atomicAdd(&sums[DB * 16 + o], acc1);                                \
        if (o == 0) {                                                       \
            atomicAdd(&cnt[DA], 1.f);                                       \
            atomicAdd(&cnt[DB], 1.f);                                       \
        }                                                                   \
    } while (0)

    LOAD_TILE(0, pA00, pA01, pA10, pA11, pX0, pX1, pDA, pDB);
    #pragma unroll
    for (int t = 0; t < EDGE_TILES; t++) {
        if ((t & 1) == 0) {
            if (t + 1 < EDGE_TILES)
                LOAD_TILE(t + 1, qA00, qA01, qA10, qA11, qX0, qX1, qDA, qDB);
            __builtin_amdgcn_sched_barrier(0);   // loads(t+1) stay above compute(t)
            COMPUTE_TILE(pA00, pA01, pA10, pA11, pX0, pX1, pDA, pDB);
        } else {
            if (t + 1 < EDGE_TILES)
                LOAD_TILE(t + 1, pA00, pA01, pA10, pA11, pX0, pX1, pDA, pDB);
            __builtin_amdgcn_sched_barrier(0);
            COMPUTE_TILE(qA00, qA01, qA10, qA11, qX0, qX1, qDA, qDB);
        }
    }
#undef LOAD_TILE
#undef COMPUTE_TILE
}

// One block per GRAPH (batch is sorted). Replaces node_kernel + head_kernel.
// Binary-search the node range [start,end); stream nodes in 16-node tiles:
// thread (j = tid>>4, o = tid&15) computes h[base+j][o]; the x row is
// accessed via intra-wave shuffle (wave = 4 j-values x 16 o-values, so
// x[n][i] lives in lane ((j&3)<<4)|i ) -- no LDS staging, no barriers, no
// serial flusher, and NO pooling atomics: per-thread register accumulators
// -> wave tree-reduce -> cross-wave LDS reduce -> fused head MLP -> out[g].
// (Passed R3-R14 with absmax 0.0; ~8 us by arithmetic.)
__global__ __launch_bounds__(256) void graph_kernel(
    const float* __restrict__ x, const int* __restrict__ batch,
    const float* __restrict__ root_w, const float* __restrict__ conv_b,
    const float* __restrict__ sums, const float* __restrict__ cnt,
    const float* __restrict__ lin1_w, const float* __restrict__ lin1_b,
    const float* __restrict__ lin2_w, const float* __restrict__ lin2_b,
    float* __restrict__ out)
{
    __shared__ float redM[4][16];
    __shared__ float redS[4][16];

    const int g   = blockIdx.x;
    const int tid = threadIdx.x;
    const int j   = tid >> 4;
    const int o   = tid & 15;
    const int jw  = j & 3;             // j within the 64-lane wave

    // root_w row o into registers: rwr[i] = root_w[o*16+i]
    float rwr[F_IN];
    #pragma unroll
    for (int r = 0; r < 4; r++) {
        const float4 v = *(const float4*)&root_w[o * 16 + 4 * r];
        rwr[4*r+0] = v.x; rwr[4*r+1] = v.y; rwr[4*r+2] = v.z; rwr[4*r+3] = v.w;
    }
    const float cb = conv_b[o];

    // Interleaved binary searches (batch sorted, block-uniform -> no
    // divergence; the two dependent-load chains overlap each other):
    //   start = lower_bound(batch, g), end = lower_bound(batch, g+1)
    int lo0 = 0, hi0 = NUM_NODES, lo1 = 0, hi1 = NUM_NODES;
    while (lo0 < hi0 || lo1 < hi1) {
        const int m0 = (lo0 + hi0) >> 1;
        const int m1 = (lo1 + hi1) >> 1;
        int b0 = 0, b1 = 0;
        if (lo0 < hi0) b0 = batch[m0];
        if (lo1 < hi1) b1 = batch[m1];
        if (lo0 < hi0) { if (b0 < g)     lo0 = m0 + 1; else hi0 = m0; }
        if (lo1 < hi1) { if (b1 < g + 1) lo1 = m1 + 1; else hi1 = m1; }
    }
    const int start = lo0, end = lo1;

    float am = 0.f, asum = 0.f;        // h >= 0, so 0 is a valid max identity

    // software-pipelined main loop (prefetch next tile's 3 loads)
    int base = start;
    float xv = 0.f, sv = 0.f, cv = 1.f;
    if (base < end) {
        const int n = base + j;
        const bool v = n < end;
        xv = v ? x[n * 16 + o]    : 0.f;
        sv = v ? sums[n * 16 + o] : 0.f;
        cv = v ? cnt[n]           : 1.f;
    }
    while (base < end) {
        const int nbase = base + 16;
        float xv1 = 0.f, sv1 = 0.f, cv1 = 1.f;
        if (nbase < end) {
            const int n1 = nbase + j;
            const bool v1 = n1 < end;
            xv1 = v1 ? x[n1 * 16 + o]    : 0.f;
            sv1 = v1 ? sums[n1 * 16 + o] : 0.f;
            cv1 = v1 ? cnt[n1]           : 1.f;
        }
        __builtin_amdgcn_sched_barrier(0);   // prefetch issues before compute

        // h-FMA order identical to old node_kernel (bit-exact per element)
        float a = cb + sv / fmaxf(cv, 1.f);
        #pragma unroll
        for (int i = 0; i < F_IN; i++)
            a = fmaf(__shfl(xv, (jw << 4) | i, 64), rwr[i], a);
        const bool v = (base + j) < end;
        const float h = v ? fmaxf(a, 0.f) : 0.f;
        am = fmaxf(am, h);
        asum += h;

        xv = xv1; sv = sv1; cv = cv1;
        base = nbase;
    }

    // reduce over j: butterfly within wave (j&3), then across 4 waves via LDS
    am   = fmaxf(am, __shfl_xor(am, 16, 64));
    am   = fmaxf(am, __shfl_xor(am, 32, 64));
    asum = asum + __shfl_xor(asum, 16, 64);
    asum = asum + __shfl_xor(asum, 32, 64);
    const int w = tid >> 6;
    if ((tid & 63) < 16) { redM[w][o] = am; redS[w][o] = asum; }
    __syncthreads();

    if (tid < 64) {                     // wave 0: final reduce + head MLP
        const int k = tid & 15;
        const float amF = fmaxf(fmaxf(redM[0][k], redM[1][k]),
                                fmaxf(redM[2][k], redM[3][k]));
        const float asF = (redS[0][k] + redS[1][k]) + (redS[2][k] + redS[3][k]);
        const float c   = fmaxf((float)(end - start), 1.f);
        const float mnF = asF / c;

        // lane k computes a_k; inner cc order matches old head_kernel
        float a = lin1_b[k];
        #pragma unroll
        for (int cc = 0; cc < 16; cc++)
            a = fmaf(__shfl(amF, cc, 64), lin1_w[k * 32 + cc], a);
        #pragma unroll
        for (int cc = 0; cc < 16; cc++)
            a = fmaf(__shfl(mnF, cc, 64), lin1_w[k * 32 + 16 + cc], a);
        const float ra = fmaxf(a, 0.f);

        // serial k-accumulation (same order as old head_kernel)
        float acc = lin2_b[0];
        #pragma unroll
        for (int k2 = 0; k2 < 16; k2++)
            acc = fmaf(__shfl(ra, k2, 64), lin2_w[k2], acc);
        if (tid == 0) out[g] = acc;
    }
}

extern "C" void kernel_launch(void* const* d_in, const int* in_sizes, int n_in,
                              void* d_out, int out_size, void* d_ws, size_t ws_size,
                              hipStream_t stream) {
    const float* x      = (const float*)d_in[0];
    const int*   ei     = (const int*)d_in[1];
    const float* ea     = (const float*)d_in[2];
    const int*   batch  = (const int*)d_in[3];
    const float* nn1_w  = (const float*)d_in[4];
    const float* nn1_b  = (const float*)d_in[5];
    const float* root_w = (const float*)d_in[6];
    const float* conv_b = (const float*)d_in[7];
    const float* lin1_w = (const float*)d_in[8];
    const float* lin1_b = (const float*)d_in[9];
    const float* lin2_w = (const float*)d_in[10];
    const float* lin2_b = (const float*)d_in[11];
    float* out = (float*)d_out;

    float* sums = (float*)d_ws;
    float* cnt  = sums + (size_t)NUM_NODES * EMB;

    const size_t zero_bytes = sizeof(float) * ((size_t)NUM_NODES * EMB + NUM_NODES);
    hipMemsetAsync(d_ws, 0, zero_bytes, stream);

    edge_kernel<<<EDGE_BLOCKS, 256, 0, stream>>>(x, ei, ea, nn1_w, nn1_b, sums, cnt);
    graph_kernel<<<NUM_GRAPHS, 256, 0, stream>>>(
        x, batch, root_w, conv_b, sums, cnt,
        lin1_w, lin1_b, lin2_w, lin2_b, out);
}